// Round 1
// baseline (1107.104 us; speedup 1.0000x reference)
//
#include <hip/hip_runtime.h>
#include <stdint.h>
#include <stddef.h>

#define MDIM 4096
#define NDIM 16384
#define KDIM 4096

typedef __bf16 bf16;
typedef __bf16 bf16x4 __attribute__((ext_vector_type(4)));
typedef __bf16 bf16x8 __attribute__((ext_vector_type(8)));
typedef float  fx4    __attribute__((ext_vector_type(4)));
typedef int    ix4    __attribute__((ext_vector_type(4)));

#define AS1(p) ((const __attribute__((address_space(1))) void*)(p))
#define AS3(p) ((__attribute__((address_space(3))) void*)(p))

// ---------------- conversion kernels ----------------
__global__ __launch_bounds__(256) void cvt_x_kernel(const fx4* __restrict__ x,
                                                    bf16x4* __restrict__ xb, int n4) {
    int i = blockIdx.x * 256 + threadIdx.x;
    if (i < n4) {
        fx4 v = x[i];
        bf16x4 o;
        o[0] = (bf16)v[0]; o[1] = (bf16)v[1]; o[2] = (bf16)v[2]; o[3] = (bf16)v[3];
        xb[i] = o;
    }
}

__global__ __launch_bounds__(256) void cvt_w_kernel(const ix4* __restrict__ q,
                                                    bf16x4* __restrict__ wb,
                                                    const float* __restrict__ zp_ptr, int n4) {
    float zp = *zp_ptr;
    int i = blockIdx.x * 256 + threadIdx.x;
    if (i < n4) {
        ix4 v = q[i];
        bf16x4 o;
        o[0] = (bf16)((float)v[0] - zp);
        o[1] = (bf16)((float)v[1] - zp);
        o[2] = (bf16)((float)v[2] - zp);
        o[3] = (bf16)((float)v[3] - zp);
        wb[i] = o;
    }
}

// ---------------- main GEMM: C[M,N] = A[M,K] * B[N,K]^T, epilogue scale+bias ----------------
// 128x128 tile, BK=32, 256 threads = 4 waves in 2x2, each wave 64x64 via 4x4 MFMA 16x16x32.
__global__ __launch_bounds__(256) void gemm_kernel(const bf16* __restrict__ A,
                                                   const bf16* __restrict__ B,
                                                   const float* __restrict__ scale_ptr,
                                                   const float* __restrict__ bias,
                                                   float* __restrict__ C) {
    constexpr int BK = 32;
    __shared__ bf16 As[128 * BK];   // row-major [128][32], 8 KB
    __shared__ bf16 Bs[128 * BK];   // row-major [128][32], 8 KB

    const int tid  = threadIdx.x;
    const int wave = tid >> 6;
    const int lane = tid & 63;

    const int bn = blockIdx.x;      // N / 128 = 128
    const int bm = blockIdx.y;      // M / 128 = 32

    // ---- staging geometry (global_load_lds, width 16B = 8 bf16 per lane) ----
    // wave w covers tile bytes [w*2048, w*2048+2048) via 2 calls of 1KB each.
    // linear off = w*2048 + j*1024 + lane*16  ->  row = w*32 + j*16 + (lane>>2), kbyte = (lane&3)*16
    const int rowStage = wave * 32 + (lane >> 2);
    const int kStage   = (lane & 3) * 8;                  // bf16 elements
    const bf16* aptr0 = A + (size_t)(bm * 128 + rowStage) * KDIM + kStage;
    const bf16* aptr1 = aptr0 + 16 * KDIM;
    const bf16* bptr0 = B + (size_t)(bn * 128 + rowStage) * KDIM + kStage;
    const bf16* bptr1 = bptr0 + 16 * KDIM;
    bf16* AsW = As + wave * 1024;    // elements; +512 for j=1
    bf16* BsW = Bs + wave * 1024;

    // ---- fragment geometry ----
    const int wm = (wave >> 1) * 64;     // wave row offset in tile
    const int wn = (wave & 1) * 64;      // wave col offset in tile
    const int fr = lane & 15;            // fragment row (m or n)
    const int fq = lane >> 4;            // quad 0..3 -> k offset fq*8
    const bf16* aRead = As + (wm + fr) * BK + fq * 8;
    const bf16* bRead = Bs + (wn + fr) * BK + fq * 8;

    fx4 acc[4][4];
#pragma unroll
    for (int mi = 0; mi < 4; ++mi)
#pragma unroll
        for (int ni = 0; ni < 4; ++ni)
            acc[mi][ni] = fx4{0.f, 0.f, 0.f, 0.f};

    const int KT = KDIM / BK;   // 128
    for (int kt = 0; kt < KT; ++kt) {
        __syncthreads();   // previous tile's consumers done
        __builtin_amdgcn_global_load_lds(AS1(aptr0), AS3(AsW),       16, 0, 0);
        __builtin_amdgcn_global_load_lds(AS1(aptr1), AS3(AsW + 512), 16, 0, 0);
        __builtin_amdgcn_global_load_lds(AS1(bptr0), AS3(BsW),       16, 0, 0);
        __builtin_amdgcn_global_load_lds(AS1(bptr1), AS3(BsW + 512), 16, 0, 0);
        aptr0 += BK; aptr1 += BK; bptr0 += BK; bptr1 += BK;
        __syncthreads();   // compiler inserts s_waitcnt vmcnt(0) before s_barrier

        bf16x8 af[4], bf[4];
#pragma unroll
        for (int i = 0; i < 4; ++i) {
            af[i] = *(const bf16x8*)(aRead + i * 16 * BK);
            bf[i] = *(const bf16x8*)(bRead + i * 16 * BK);
        }
#pragma unroll
        for (int mi = 0; mi < 4; ++mi)
#pragma unroll
            for (int ni = 0; ni < 4; ++ni)
                acc[mi][ni] = __builtin_amdgcn_mfma_f32_16x16x32_bf16(af[mi], bf[ni], acc[mi][ni], 0, 0, 0);
    }

    // ---- epilogue: C/D layout col = lane&15, row = (lane>>4)*4 + reg ----
    const float s = *scale_ptr;
    float bv[4];
#pragma unroll
    for (int ni = 0; ni < 4; ++ni)
        bv[ni] = bias[bn * 128 + wn + ni * 16 + fr];

    const int c0 = bn * 128 + wn + fr;
    const int r0 = bm * 128 + wm + fq * 4;
#pragma unroll
    for (int mi = 0; mi < 4; ++mi) {
#pragma unroll
        for (int i = 0; i < 4; ++i) {
            float* crow = C + (size_t)(r0 + mi * 16 + i) * NDIM + c0;
#pragma unroll
            for (int ni = 0; ni < 4; ++ni)
                crow[ni * 16] = s * acc[mi][ni][i] + bv[ni];
        }
    }
}

// ---------------- slow-but-correct fallback (only if ws_size is too small) ----------------
__global__ __launch_bounds__(256) void naive_kernel(const float* __restrict__ x,
                                                    const int* __restrict__ q,
                                                    const float* __restrict__ sp,
                                                    const float* __restrict__ zpp,
                                                    const float* __restrict__ bias,
                                                    float* __restrict__ out) {
    float s = *sp, zp = *zpp;
    size_t idx = (size_t)blockIdx.x * 256 + threadIdx.x;
    int m = (int)(idx / NDIM);
    int n = (int)(idx % NDIM);
    const fx4* xr = (const fx4*)(x + (size_t)m * KDIM);
    const ix4* qr = (const ix4*)(q + (size_t)n * KDIM);
    float acc = 0.f;
    for (int k = 0; k < KDIM / 4; ++k) {
        fx4 xv = xr[k];
        ix4 qv = qr[k];
        acc += xv[0] * ((float)qv[0] - zp) + xv[1] * ((float)qv[1] - zp)
             + xv[2] * ((float)qv[2] - zp) + xv[3] * ((float)qv[3] - zp);
    }
    out[idx] = s * acc + bias[n];
}

extern "C" void kernel_launch(void* const* d_in, const int* in_sizes, int n_in,
                              void* d_out, int out_size, void* d_ws, size_t ws_size,
                              hipStream_t stream) {
    const float* x     = (const float*)d_in[0];
    const int*   q     = (const int*)d_in[1];
    const float* scale = (const float*)d_in[2];
    const float* zp    = (const float*)d_in[3];
    const float* bias  = (const float*)d_in[4];
    float* out = (float*)d_out;

    const size_t need = ((size_t)MDIM * KDIM + (size_t)NDIM * KDIM) * sizeof(bf16); // 160 MiB
    if (ws_size >= need) {
        bf16* xb = (bf16*)d_ws;
        bf16* wb = xb + (size_t)MDIM * KDIM;

        const int nx4 = MDIM * KDIM / 4;   // 4,194,304
        const int nw4 = NDIM * KDIM / 4;   // 16,777,216
        cvt_x_kernel<<<nx4 / 256, 256, 0, stream>>>((const fx4*)x, (bf16x4*)xb, nx4);
        cvt_w_kernel<<<nw4 / 256, 256, 0, stream>>>((const ix4*)q, (bf16x4*)wb, zp, nw4);

        dim3 grid(NDIM / 128, MDIM / 128);
        gemm_kernel<<<grid, 256, 0, stream>>>(xb, wb, scale, bias, out);
    } else {
        naive_kernel<<<((size_t)MDIM * NDIM) / 256, 256, 0, stream>>>(x, q, scale, zp, bias, out);
    }
}

// Round 2
// 1091.932 us; speedup vs baseline: 1.0139x; 1.0139x over previous
//
#include <hip/hip_runtime.h>
#include <stdint.h>
#include <stddef.h>

#define MDIM 4096
#define NDIM 16384
#define KDIM 4096

typedef __bf16 bf16;
typedef __bf16 bf16x8 __attribute__((ext_vector_type(8)));
typedef float  fx4    __attribute__((ext_vector_type(4)));
typedef int    ix4    __attribute__((ext_vector_type(4)));

#define AS1(p) ((const __attribute__((address_space(1))) void*)(p))
#define AS3(p) ((__attribute__((address_space(3))) void*)(p))

// ---------------- conversion kernels (16B loads, 16B stores, 8 elem/thread) ----------------
__global__ __launch_bounds__(256) void cvt_x_kernel(const fx4* __restrict__ x,
                                                    bf16x8* __restrict__ xb, int n8) {
    int i = blockIdx.x * 256 + threadIdx.x;
    if (i < n8) {
        fx4 v0 = x[2 * i];
        fx4 v1 = x[2 * i + 1];
        bf16x8 o;
        o[0] = (bf16)v0[0]; o[1] = (bf16)v0[1]; o[2] = (bf16)v0[2]; o[3] = (bf16)v0[3];
        o[4] = (bf16)v1[0]; o[5] = (bf16)v1[1]; o[6] = (bf16)v1[2]; o[7] = (bf16)v1[3];
        xb[i] = o;
    }
}

__global__ __launch_bounds__(256) void cvt_w_kernel(const ix4* __restrict__ q,
                                                    bf16x8* __restrict__ wb,
                                                    const float* __restrict__ zp_ptr, int n8) {
    float zp = *zp_ptr;
    int i = blockIdx.x * 256 + threadIdx.x;
    if (i < n8) {
        ix4 v0 = q[2 * i];
        ix4 v1 = q[2 * i + 1];
        bf16x8 o;
        o[0] = (bf16)((float)v0[0] - zp); o[1] = (bf16)((float)v0[1] - zp);
        o[2] = (bf16)((float)v0[2] - zp); o[3] = (bf16)((float)v0[3] - zp);
        o[4] = (bf16)((float)v1[0] - zp); o[5] = (bf16)((float)v1[1] - zp);
        o[6] = (bf16)((float)v1[2] - zp); o[7] = (bf16)((float)v1[3] - zp);
        wb[i] = o;
    }
}

// ---------------- main GEMM: C[M,N] = A[M,K] * B[N,K]^T, epilogue scale+bias ----------------
// 128x128 tile, BK=32, 256 threads = 4 waves in 2x2, each wave 64x64 via 4x4 MFMA 16x16x32.
// LDS XOR swizzle: stored chunk c (16B units) of row r holds global chunk c ^ ((r>>1)&3).
// Implemented by permuting the staging lane's global k-offset; global_load_lds deposit
// (wave-uniform base + lane*16) is untouched. Kills the 4-way chunk-column conflicts:
// every aligned 8-lane group of a ds_read_b128 now covers all 8 four-bank columns.
__global__ __launch_bounds__(256) void gemm_kernel(const bf16* __restrict__ A,
                                                   const bf16* __restrict__ B,
                                                   const float* __restrict__ scale_ptr,
                                                   const float* __restrict__ bias,
                                                   float* __restrict__ C) {
    constexpr int BK = 32;
    __shared__ bf16 As[128 * BK];   // [128][32] swizzled, 8 KB
    __shared__ bf16 Bs[128 * BK];

    const int tid  = threadIdx.x;
    const int wave = tid >> 6;
    const int lane = tid & 63;

    const int bn = blockIdx.x;      // N / 128 = 128
    const int bm = blockIdx.y;      // M / 128 = 32

    // ---- staging geometry ----
    // LDS linear offset = wave*2048 + j*1024 + lane*16 bytes
    //   -> row r = wave*32 + j*16 + (lane>>2), stored chunk c = lane&3.
    // Want stored chunk c to hold global chunk c ^ ((r>>1)&3); ((r>>1)&3) == (lane>>3)&3.
    const int rowStage  = wave * 32 + (lane >> 2);
    const int srcChunk  = (lane & 3) ^ ((lane >> 3) & 3);
    const int kStage    = srcChunk * 8;                   // bf16 elements
    const bf16* aptr0 = A + (size_t)(bm * 128 + rowStage) * KDIM + kStage;
    const bf16* aptr1 = aptr0 + 16 * KDIM;
    const bf16* bptr0 = B + (size_t)(bn * 128 + rowStage) * KDIM + kStage;
    const bf16* bptr1 = bptr0 + 16 * KDIM;
    bf16* AsW = As + wave * 1024;    // elements; +512 for j=1
    bf16* BsW = Bs + wave * 1024;

    // ---- fragment geometry ----
    const int wm = (wave >> 1) * 64;
    const int wn = (wave & 1) * 64;
    const int fr = lane & 15;            // fragment row (m or n)
    const int fq = lane >> 4;            // quad -> k offset fq*8
    const int sw = (fr >> 1) & 3;        // swizzle (invariant under wm/wn/mi*16)
    const bf16* aRead = As + (wm + fr) * BK + (fq ^ sw) * 8;
    const bf16* bRead = Bs + (wn + fr) * BK + (fq ^ sw) * 8;

    fx4 acc[4][4];
#pragma unroll
    for (int mi = 0; mi < 4; ++mi)
#pragma unroll
        for (int ni = 0; ni < 4; ++ni)
            acc[mi][ni] = fx4{0.f, 0.f, 0.f, 0.f};

    const int KT = KDIM / BK;   // 128
    for (int kt = 0; kt < KT; ++kt) {
        __syncthreads();   // previous tile's consumers done
        __builtin_amdgcn_global_load_lds(AS1(aptr0), AS3(AsW),       16, 0, 0);
        __builtin_amdgcn_global_load_lds(AS1(aptr1), AS3(AsW + 512), 16, 0, 0);
        __builtin_amdgcn_global_load_lds(AS1(bptr0), AS3(BsW),       16, 0, 0);
        __builtin_amdgcn_global_load_lds(AS1(bptr1), AS3(BsW + 512), 16, 0, 0);
        aptr0 += BK; aptr1 += BK; bptr0 += BK; bptr1 += BK;
        __syncthreads();

        bf16x8 af[4], bfr[4];
#pragma unroll
        for (int i = 0; i < 4; ++i) {
            af[i]  = *(const bf16x8*)(aRead + i * 16 * BK);
            bfr[i] = *(const bf16x8*)(bRead + i * 16 * BK);
        }
#pragma unroll
        for (int mi = 0; mi < 4; ++mi)
#pragma unroll
            for (int ni = 0; ni < 4; ++ni)
                acc[mi][ni] = __builtin_amdgcn_mfma_f32_16x16x32_bf16(af[mi], bfr[ni], acc[mi][ni], 0, 0, 0);
    }

    // ---- epilogue: C/D layout col = lane&15, row = (lane>>4)*4 + reg ----
    const float s = *scale_ptr;
    float bv[4];
#pragma unroll
    for (int ni = 0; ni < 4; ++ni)
        bv[ni] = bias[bn * 128 + wn + ni * 16 + fr];

    const int c0 = bn * 128 + wn + fr;
    const int r0 = bm * 128 + wm + fq * 4;
#pragma unroll
    for (int mi = 0; mi < 4; ++mi) {
#pragma unroll
        for (int i = 0; i < 4; ++i) {
            float* crow = C + (size_t)(r0 + mi * 16 + i) * NDIM + c0;
#pragma unroll
            for (int ni = 0; ni < 4; ++ni)
                crow[ni * 16] = s * acc[mi][ni][i] + bv[ni];
        }
    }
}

// ---------------- slow-but-correct fallback (only if ws_size is too small) ----------------
__global__ __launch_bounds__(256) void naive_kernel(const float* __restrict__ x,
                                                    const int* __restrict__ q,
                                                    const float* __restrict__ sp,
                                                    const float* __restrict__ zpp,
                                                    const float* __restrict__ bias,
                                                    float* __restrict__ out) {
    float s = *sp, zp = *zpp;
    size_t idx = (size_t)blockIdx.x * 256 + threadIdx.x;
    int m = (int)(idx / NDIM);
    int n = (int)(idx % NDIM);
    const fx4* xr = (const fx4*)(x + (size_t)m * KDIM);
    const ix4* qr = (const ix4*)(q + (size_t)n * KDIM);
    float acc = 0.f;
    for (int k = 0; k < KDIM / 4; ++k) {
        fx4 xv = xr[k];
        ix4 qv = qr[k];
        acc += xv[0] * ((float)qv[0] - zp) + xv[1] * ((float)qv[1] - zp)
             + xv[2] * ((float)qv[2] - zp) + xv[3] * ((float)qv[3] - zp);
    }
    out[idx] = s * acc + bias[n];
}

extern "C" void kernel_launch(void* const* d_in, const int* in_sizes, int n_in,
                              void* d_out, int out_size, void* d_ws, size_t ws_size,
                              hipStream_t stream) {
    const float* x     = (const float*)d_in[0];
    const int*   q     = (const int*)d_in[1];
    const float* scale = (const float*)d_in[2];
    const float* zp    = (const float*)d_in[3];
    const float* bias  = (const float*)d_in[4];
    float* out = (float*)d_out;

    const size_t need = ((size_t)MDIM * KDIM + (size_t)NDIM * KDIM) * sizeof(bf16); // 160 MiB
    if (ws_size >= need) {
        bf16* xb = (bf16*)d_ws;
        bf16* wb = xb + (size_t)MDIM * KDIM;

        const int nx8 = MDIM * KDIM / 8;   // 2,097,152
        const int nw8 = NDIM * KDIM / 8;   // 8,388,608
        cvt_x_kernel<<<nx8 / 256, 256, 0, stream>>>((const fx4*)x, (bf16x8*)xb, nx8);
        cvt_w_kernel<<<nw8 / 256, 256, 0, stream>>>((const ix4*)q, (bf16x8*)wb, zp, nw8);

        dim3 grid(NDIM / 128, MDIM / 128);
        gemm_kernel<<<grid, 256, 0, stream>>>(xb, wb, scale, bias, out);
    } else {
        naive_kernel<<<((size_t)MDIM * NDIM) / 256, 256, 0, stream>>>(x, q, scale, zp, bias, out);
    }
}